// Round 1
// baseline (211.398 us; speedup 1.0000x reference)
//
#include <hip/hip_runtime.h>
#include <math.h>

// Problem constants (from reference)
#define T_STEPS   256
#define N_NEUR    2048
#define N_BATCH   32

// Time-chunked register double-buffering.
// CHUNK timesteps (2 loads each) are prefetched into one named register
// buffer while the other buffer's chunk is consumed by the (serially
// dependent) scan. All array indices are compile-time constants so the
// buffers live in VGPRs, never scratch. With 32 independent loads in
// flight per wave (8 KB) x 4 waves/CU = 32 KB/CU, we exceed the
// bandwidth-delay product (~9 KB/CU) and become HBM-throughput-bound
// instead of latency-bound.
#define CHUNK   16
#define NCHUNK  (T_STEPS / CHUNK)   // 16

// fp discipline: reference (XLA float32) rounds mul and add separately —
// use __fmul_rn/__fadd_rn so fp-contract=fast cannot fuse into FMA and
// flip ulp-near-threshold spikes. Op order identical to the passing kernel.

__global__ __launch_bounds__(256) void snn_scan_kernel(
    const float* __restrict__ in,
    float* __restrict__ out,
    float a_mem, float a_s0, float a_s1)
{
    const int tid = blockIdx.x * blockDim.x + threadIdx.x;   // 0..65535
    const int n = tid & (N_NEUR - 1);
    const int b = tid >> 11;

    const float* pin = in + (size_t)b * T_STEPS * 2 * N_NEUR + n;
    float* pout      = out + (size_t)b * T_STEPS * N_NEUR + n;

    float vmem = 0.0f;
    float i0 = 0.0f;
    float i1 = 0.0f;

    // Two named double-buffers (syn0 / syn1 inputs per timestep).
    float xa0[CHUNK], xb0[CHUNK];
    float xa1[CHUNK], xb1[CHUNK];

    // Issue one chunk's worth of loads as a single independent burst.
#define LOADC(XA, XB, CIDX)                                                  \
    {                                                                        \
        const float* p_ = pin + (size_t)(CIDX) * CHUNK * (2 * N_NEUR);       \
        _Pragma("unroll")                                                    \
        for (int k = 0; k < CHUNK; ++k) {                                    \
            XA[k] = p_[(size_t)k * (2 * N_NEUR)];                            \
            XB[k] = p_[(size_t)k * (2 * N_NEUR) + N_NEUR];                   \
        }                                                                    \
    }

    // Consume one chunk from registers; op order matches reference exactly.
#define COMPUTEC(XA, XB, CIDX)                                               \
    {                                                                        \
        float* po_ = pout + (size_t)(CIDX) * CHUNK * N_NEUR;                 \
        _Pragma("unroll")                                                    \
        for (int k = 0; k < CHUNK; ++k) {                                    \
            i0 = __fadd_rn(__fmul_rn(a_s0, i0), XA[k]);                      \
            i1 = __fadd_rn(__fmul_rn(a_s1, i1), XB[k]);                      \
            const float ssum = __fadd_rn(i0, i1);                            \
            vmem = __fadd_rn(__fmul_rn(a_mem, vmem), ssum);                  \
            const float vs = __fsub_rn(vmem, 1.0f);                          \
            const bool fired = (vs > 0.0f);                                  \
            po_[(size_t)k * N_NEUR] = fired ? 1.0f : 0.0f;                   \
            vmem = fired ? vs : vmem;                                        \
        }                                                                    \
    }

    // Prologue: fill both buffers (chunks 0 and 1 in flight together).
    LOADC(xa0, xb0, 0);
    LOADC(xa1, xb1, 1);

    // Steady state: compute chunk c from buf0 while buf1 (chunk c+1) is in
    // flight; refill buf0 with chunk c+2 before consuming buf1; etc.
    for (int c = 0; c < NCHUNK; c += 2) {
        COMPUTEC(xa0, xb0, c);
        if (c + 2 < NCHUNK) LOADC(xa0, xb0, c + 2);
        COMPUTEC(xa1, xb1, c + 1);
        if (c + 3 < NCHUNK) LOADC(xa1, xb1, c + 3);
    }

#undef LOADC
#undef COMPUTEC
}

extern "C" void kernel_launch(void* const* d_in, const int* in_sizes, int n_in,
                              void* d_out, int out_size, void* d_ws, size_t ws_size,
                              hipStream_t stream) {
    const float* in = (const float*)d_in[0];
    float* out = (float*)d_out;

    // Correctly-rounded float32 decay constants of exp on the float32-rounded
    // argument: matches jnp.exp(jnp.float32(-1/tau)).
    const float a_s0  = (float)exp((double)(-1.0f / 5.0f));   // tau_syn[0] = 5
    const float a_s1  = (float)exp((double)(-1.0f / 10.0f));  // tau_syn[1] = 10
    const float a_mem = (float)exp((double)(-1.0f / 10.0f));  // tau_mem    = 10

    const int total_threads = N_BATCH * N_NEUR;  // 65536
    dim3 block(256);
    dim3 grid(total_threads / 256);              // 256 blocks -> 1 per CU

    snn_scan_kernel<<<grid, block, 0, stream>>>(in, out, a_mem, a_s0, a_s1);
}

// Round 2
// 211.366 us; speedup vs baseline: 1.0001x; 1.0001x over previous
//
#include <hip/hip_runtime.h>
#include <math.h>

// Problem constants (from reference)
#define T_STEPS   256
#define N_NEUR    2048
#define N_BATCH   32

// float2-per-thread variant: each thread owns neurons (2k, 2k+1) of one
// batch row. 32768 threads = 512 waves = 2 waves/CU. Per-wave loads are
// 64 lanes x 8 B = 512 B contiguous (dwordx2), halving load/store
// instruction count vs the scalar version, and giving each thread two
// independent scan chains (ILP on the serially-dependent VALU chain).
//
// Register double-buffer: CHUNK timesteps (2x float2 loads each) prefetch
// into one named buffer while the other is consumed. All indices are
// compile-time constants so buffers stay in VGPRs (never scratch).
// ~8 KB/wave in flight >> the per-wave share of the bandwidth-delay
// product (~4.5 KB at 2 waves/CU).
//
// Nontemporal loads/stores: both streams are touch-once; nt hints skip
// cache-allocate churn.
#define CHUNK   8
#define NCHUNK  (T_STEPS / CHUNK)   // 32

typedef float f32x2 __attribute__((ext_vector_type(2)));

// fp discipline: reference (XLA float32) rounds mul and add separately —
// per-component __fmul_rn/__fadd_rn so fp-contract=fast cannot fuse into
// FMA and flip ulp-near-threshold spikes. Op order per neuron is identical
// to the previously passing kernel.

__global__ __launch_bounds__(128) void snn_scan_kernel(
    const float* __restrict__ in,
    float* __restrict__ out,
    float a_mem, float a_s0, float a_s1)
{
    const int tid = blockIdx.x * blockDim.x + threadIdx.x;   // 0..32767
    const int n2 = tid & (N_NEUR / 2 - 1);                   // float2 index
    const int b  = tid >> 10;

    const float* pin = in + (size_t)b * T_STEPS * 2 * N_NEUR + 2 * n2;
    float* pout      = out + (size_t)b * T_STEPS * N_NEUR + 2 * n2;

    f32x2 vmem = {0.0f, 0.0f};
    f32x2 i0   = {0.0f, 0.0f};
    f32x2 i1   = {0.0f, 0.0f};

    // Two named double-buffers (syn0 / syn1 inputs per timestep).
    f32x2 xa0[CHUNK], xb0[CHUNK];
    f32x2 xa1[CHUNK], xb1[CHUNK];

    // Issue one chunk's worth of loads as a single independent burst.
#define LOADC(XA, XB, CIDX)                                                  \
    {                                                                        \
        const float* p_ = pin + (size_t)(CIDX) * CHUNK * (2 * N_NEUR);       \
        _Pragma("unroll")                                                    \
        for (int k = 0; k < CHUNK; ++k) {                                    \
            XA[k] = __builtin_nontemporal_load(                              \
                (const f32x2*)(p_ + (size_t)k * (2 * N_NEUR)));              \
            XB[k] = __builtin_nontemporal_load(                              \
                (const f32x2*)(p_ + (size_t)k * (2 * N_NEUR) + N_NEUR));     \
        }                                                                    \
    }

    // Consume one chunk from registers; op order matches reference exactly.
#define COMPUTEC(XA, XB, CIDX)                                               \
    {                                                                        \
        float* po_ = pout + (size_t)(CIDX) * CHUNK * N_NEUR;                 \
        _Pragma("unroll")                                                    \
        for (int k = 0; k < CHUNK; ++k) {                                    \
            const f32x2 x0 = XA[k];                                          \
            const f32x2 x1 = XB[k];                                          \
            i0.x = __fadd_rn(__fmul_rn(a_s0, i0.x), x0.x);                   \
            i0.y = __fadd_rn(__fmul_rn(a_s0, i0.y), x0.y);                   \
            i1.x = __fadd_rn(__fmul_rn(a_s1, i1.x), x1.x);                   \
            i1.y = __fadd_rn(__fmul_rn(a_s1, i1.y), x1.y);                   \
            const float sx = __fadd_rn(i0.x, i1.x);                          \
            const float sy = __fadd_rn(i0.y, i1.y);                          \
            vmem.x = __fadd_rn(__fmul_rn(a_mem, vmem.x), sx);                \
            vmem.y = __fadd_rn(__fmul_rn(a_mem, vmem.y), sy);                \
            const float vsx = __fsub_rn(vmem.x, 1.0f);                       \
            const float vsy = __fsub_rn(vmem.y, 1.0f);                       \
            const bool fx = (vsx > 0.0f);                                    \
            const bool fy = (vsy > 0.0f);                                    \
            f32x2 sp;                                                        \
            sp.x = fx ? 1.0f : 0.0f;                                         \
            sp.y = fy ? 1.0f : 0.0f;                                         \
            __builtin_nontemporal_store(                                     \
                sp, (f32x2*)(po_ + (size_t)k * N_NEUR));                     \
            vmem.x = fx ? vsx : vmem.x;                                      \
            vmem.y = fy ? vsy : vmem.y;                                      \
        }                                                                    \
    }

    // Prologue: fill both buffers (chunks 0 and 1 in flight together).
    LOADC(xa0, xb0, 0);
    LOADC(xa1, xb1, 1);

    // Steady state: compute chunk c from buf0 while buf1 (chunk c+1) is in
    // flight; refill buf0 with chunk c+2 before consuming buf1; etc.
    for (int c = 0; c < NCHUNK; c += 2) {
        COMPUTEC(xa0, xb0, c);
        if (c + 2 < NCHUNK) LOADC(xa0, xb0, c + 2);
        COMPUTEC(xa1, xb1, c + 1);
        if (c + 3 < NCHUNK) LOADC(xa1, xb1, c + 3);
    }

#undef LOADC
#undef COMPUTEC
}

extern "C" void kernel_launch(void* const* d_in, const int* in_sizes, int n_in,
                              void* d_out, int out_size, void* d_ws, size_t ws_size,
                              hipStream_t stream) {
    const float* in = (const float*)d_in[0];
    float* out = (float*)d_out;

    // Correctly-rounded float32 decay constants of exp on the float32-rounded
    // argument: matches jnp.exp(jnp.float32(-1/tau)).
    const float a_s0  = (float)exp((double)(-1.0f / 5.0f));   // tau_syn[0] = 5
    const float a_s1  = (float)exp((double)(-1.0f / 10.0f));  // tau_syn[1] = 10
    const float a_mem = (float)exp((double)(-1.0f / 10.0f));  // tau_mem    = 10

    const int total_threads = N_BATCH * N_NEUR / 2;  // 32768 (float2/thread)
    dim3 block(128);
    dim3 grid(total_threads / 128);                  // 256 blocks -> 1 per CU

    snn_scan_kernel<<<grid, block, 0, stream>>>(in, out, a_mem, a_s0, a_s1);
}